// Round 6
// baseline (1221.056 us; speedup 1.0000x reference)
//
#include <hip/hip_runtime.h>
#include <hip/hip_bf16.h>
#include <math.h>

// Problem constants (CausalSelfAttention: B=4, S=2048, Dm=2048, H=16, Hd=128)
// Inputs/outputs are FP32 (per reference); compute in bf16 MFMA w/ fp32 accum.
#define SEQ   2048
#define DM    2048
#define NH    16
#define HD    128
#define MROWS 8192   // B*S

typedef __bf16 bf16x8 __attribute__((ext_vector_type(8)));
typedef __bf16 bf16x4 __attribute__((ext_vector_type(4)));
typedef float  f32x4  __attribute__((ext_vector_type(4)));

#define MFMA16(a, b, c) __builtin_amdgcn_mfma_f32_16x16x32_bf16((a), (b), (c), 0, 0, 0)

__device__ __forceinline__ void g2l16(const void* g, void* l) {
    __builtin_amdgcn_global_load_lds(
        (const __attribute__((address_space(1))) void*)g,
        (__attribute__((address_space(3))) void*)l, 16, 0, 0);
}

// ---------------------------------------------------------------------------
// Fused prep: blocks [0,16384): transpose+convert the 4 weights
//             blocks [16384, 24576): elementwise x fp32->bf16
// ---------------------------------------------------------------------------
__global__ void prep_fused(const float* __restrict__ x,
                           const float* __restrict__ s0,
                           const float* __restrict__ s1,
                           const float* __restrict__ s2,
                           const float* __restrict__ s3,
                           __bf16* __restrict__ xb,
                           __bf16* __restrict__ wdst) {
    const int bx = blockIdx.x;
    if (bx < 16384) {
        __shared__ float t[32][33];
        const int z = bx >> 12, rem = bx & 4095;
        const float* src = (z == 0) ? s0 : (z == 1) ? s1 : (z == 2) ? s2 : s3;
        __bf16* d = wdst + (size_t)z * DM * DM;
        const int c0 = (rem & 63) * 32, r0 = (rem >> 6) * 32;
        for (int i = threadIdx.y; i < 32; i += 8)
            t[i][threadIdx.x] = src[(size_t)(r0 + i) * DM + c0 + threadIdx.x];
        __syncthreads();
        for (int i = threadIdx.y; i < 32; i += 8)
            d[(size_t)(c0 + i) * DM + r0 + threadIdx.x] = (__bf16)t[threadIdx.x][i];
    } else {
        const int tid = threadIdx.y * 32 + threadIdx.x;
        const size_t i0 = (((size_t)(bx - 16384)) * 256 + tid) * 8;
        if (i0 + 8 <= (size_t)MROWS * DM) {
            f32x4 a = *(const f32x4*)(x + i0);
            f32x4 b = *(const f32x4*)(x + i0 + 4);
            bf16x8 o;
#pragma unroll
            for (int j = 0; j < 4; ++j) { o[j] = (__bf16)a[j]; o[4 + j] = (__bf16)b[j]; }
            *(bf16x8*)(xb + i0) = o;
        }
    }
}

// ---------------------------------------------------------------------------
// GEMM (m97 structure + XOR bank swizzle): C[M,N] = A[M,K]*Bt[N,K]^T + bias
// 128x128 tile, BK=32, 4 waves in 2x2, each wave 64x64 via 4x4 MFMA 16x16x32.
// MODE 0: fused QKV — Bt is [3*DM, DM] (WqT;WkT;WvT).
//         proj 0/1 (Q,K): bf16 to [2][B,H,S,D] via Cout_.
//         proj 2   (V)  : bf16 to Vt_[B,H,D,S] via per-wave LDS transpose
//                         (kills the standalone V-transpose dispatch).
// MODE 1: final proj — fp32 flat [M, DM] to Cout_.
// ---------------------------------------------------------------------------
template <int MODE>
__global__ __launch_bounds__(256) void gemm_bt(const __bf16* __restrict__ A,
                                               const __bf16* __restrict__ Bt,
                                               const float* __restrict__ b0,
                                               const float* __restrict__ b1,
                                               const float* __restrict__ b2,
                                               void* __restrict__ Cout_,
                                               __bf16* __restrict__ Vt_) {
    constexpr int K = DM;
    // 9216 elem = max(staging 8192, epilogue-transpose 4 waves x 32 x 72)
    __shared__ __bf16 smem[9216];
    __bf16* As = smem;
    __bf16* Bs = smem + 4096;
    const int tid  = threadIdx.x;
    const int wave = tid >> 6, lane = tid & 63;
    const int quad = lane >> 4, l16 = lane & 15;
    const int bm = blockIdx.x * 128, bn = blockIdx.y * 128;
    const int wm = (wave >> 1) * 64, wn = (wave & 1) * 64;

    const int proj = (MODE == 0) ? (bn >> 11) : 0;               // block-uniform
    const float* bias = (MODE == 0) ? (proj == 0 ? b0 : (proj == 1 ? b1 : b2)) : b0;

    f32x4 acc[4][4];
#pragma unroll
    for (int i = 0; i < 4; ++i)
#pragma unroll
        for (int j = 0; j < 4; ++j) acc[i][j] = (f32x4){0.f, 0.f, 0.f, 0.f};

    // staging source chunk swizzle: slot (lane&3) holds global chunk c
    const int srow = (lane >> 2);                  // row within 16-row region
    const int sc   = (lane & 3) ^ ((lane >> 3) & 3);
    // fragment read chunk swizzle
    const int rswz = (l16 >> 1) & 3;

    for (int k0 = 0; k0 < K; k0 += 32) {
        __syncthreads();
#pragma unroll
        for (int j = 0; j < 2; ++j) {
            const int region = wave + 4 * j;              // 0..7, 1KB regions
            const int row    = region * 16 + srow;        // 0..127
            g2l16(A  + (size_t)(bm + row) * K + k0 + sc * 8, As + region * 512);
            g2l16(Bt + (size_t)(bn + row) * K + k0 + sc * 8, Bs + region * 512);
        }
        __syncthreads();

        bf16x8 af[4], bf[4];
#pragma unroll
        for (int i = 0; i < 4; ++i)
            af[i] = *(const bf16x8*)(As + (wm + i * 16 + l16) * 32 + (quad ^ rswz) * 8);
#pragma unroll
        for (int j = 0; j < 4; ++j)
            bf[j] = *(const bf16x8*)(Bs + (wn + j * 16 + l16) * 32 + (quad ^ rswz) * 8);
#pragma unroll
        for (int i = 0; i < 4; ++i)
#pragma unroll
            for (int j = 0; j < 4; ++j) acc[i][j] = MFMA16(af[i], bf[j], acc[i][j]);
    }

    if (MODE == 0 && proj == 2) {
        // V epilogue: transpose 64x64 wave chunk through LDS, emit [B,H,D,S].
        __syncthreads();                       // all waves done reading As/Bs
        __bf16* wb = smem + wave * 2304;       // 32 x 72 per wave
        const int b = bm >> 11;
        const int rrow = lane >> 3, cch = lane & 7;
#pragma unroll
        for (int hp = 0; hp < 2; ++hp) {
            // write transposed [n][m] rows, b64-packed over r (consecutive m)
#pragma unroll
            for (int j2 = 0; j2 < 2; ++j2) {
                const int j = hp * 2 + j2;
                const int n = (bn + wn + j * 16 + l16) & (DM - 1);
                const float bia = bias[n];
#pragma unroll
                for (int i = 0; i < 4; ++i) {
                    bf16x4 pk;
#pragma unroll
                    for (int r = 0; r < 4; ++r) pk[r] = (__bf16)(acc[i][j][r] + bia);
                    *(bf16x4*)(wb + (j2 * 16 + l16) * 72 + i * 16 + quad * 4) = pk;
                }
            }
            // read rows along m, store 16B-coalesced along s
#pragma unroll
            for (int p = 0; p < 4; ++p) {
                const int nrel  = p * 8 + rrow;            // 0..31
                const int d_loc = hp * 32 + nrel;          // 0..63
                const int n = (bn + wn + d_loc) & (DM - 1);
                const int h = n >> 7, d = n & (HD - 1);
                bf16x8 v = *(const bf16x8*)(wb + nrel * 72 + cch * 8);
                const int s = (bm & (SEQ - 1)) + wm + cch * 8;
                *(bf16x8*)(Vt_ + ((size_t)((b * NH + h) * HD + d)) * SEQ + s) = v;
            }
        }
        return;
    }

#pragma unroll
    for (int i = 0; i < 4; ++i)
#pragma unroll
        for (int j = 0; j < 4; ++j)
#pragma unroll
            for (int r = 0; r < 4; ++r) {
                const int m  = bm + wm + i * 16 + quad * 4 + r;
                const int n3 = bn + wn + j * 16 + l16;
                const int n  = (MODE == 0) ? (n3 & (DM - 1)) : n3;
                const float v = acc[i][j][r] + bias[n];
                if (MODE == 0) {
                    const int b = m >> 11, s = m & (SEQ - 1);
                    const int h = n >> 7, d = n & (HD - 1);
                    ((__bf16*)Cout_)[(size_t)proj * MROWS * DM +
                                     ((size_t)((b * NH + h) * SEQ + s)) * HD + d] = (__bf16)v;
                } else {
                    ((float*)Cout_)[(size_t)m * DM + n] = v;
                }
            }
}

// ---------------------------------------------------------------------------
// Flash attention fwd, causal — transposed-S, TWO q-strips per wave.
// Q,K: [B,H,S,D] bf16; Vt: [B,H,D,S] bf16.
// Block = 256 threads = 4 waves x 32 queries = 128 q; K-tiles of 64 keys.
// Each Ks/Vs fragment read feeds 2 MFMAs (one per strip) -> LDS-read traffic
// per query halved vs R5 (fa was LDS-throughput bound).
// Ks/Vs XOR-swizzled (chunk c -> slot c^(row&7)); P^T stride 72.
// blockIdx.x REVERSED so heavy (many-k-tile) blocks dispatch first.
// ---------------------------------------------------------------------------
__global__ __launch_bounds__(256) void fa_fwd(const __bf16* __restrict__ Q,
                                              const __bf16* __restrict__ Kg,
                                              const __bf16* __restrict__ Vt,
                                              __bf16* __restrict__ O) {
    __shared__ __bf16 Ks[64 * 128];     // [key][d] swizzled        16KB
    __shared__ __bf16 Vs[128 * 64];     // [d][key] swizzled        16KB
    __shared__ __bf16 Pt[4][32 * 72];   // per-wave P^T [q][key]    18KB
    const int tid  = threadIdx.x;
    const int wave = tid >> 6, lane = tid & 63;
    const int quad = lane >> 4, l16 = lane & 15;
    const int bh = blockIdx.y;          // b*NH + h
    const int bx = gridDim.x - 1 - blockIdx.x;
    const int q0 = bx * 128;
    const int qrow0 = q0 + wave * 32;   // this wave's 32 query rows
    __bf16* Pw = &Pt[wave][0];

    // Q B-fragments for both strips (strip s: queries qrow0+16s .. +15)
    bf16x8 qf0[4], qf1[4];
    const __bf16* qr0 = Q + (size_t)(bh * SEQ + qrow0 + l16) * HD;
#pragma unroll
    for (int kc = 0; kc < 4; ++kc) {
        qf0[kc] = *(const bf16x8*)(qr0 + kc * 32 + quad * 8);
        qf1[kc] = *(const bf16x8*)(qr0 + 16 * HD + kc * 32 + quad * 8);
    }

    float m0 = -INFINITY, l0 = 0.f, m1 = -INFINITY, l1 = 0.f;
    f32x4 o0[8], o1[8];
#pragma unroll
    for (int ot = 0; ot < 8; ++ot) {
        o0[ot] = (f32x4){0.f, 0.f, 0.f, 0.f};
        o1[ot] = (f32x4){0.f, 0.f, 0.f, 0.f};
    }

    const float sl2 = 0.08838834764831845f * 1.4426950408889634f;  // scale*log2(e)

    const int ntiles = bx * 2 + 2;      // keys up to q0+127
    for (int kt = 0; kt < ntiles; ++kt) {
        const int k0 = kt * 64;
        __syncthreads();
        // ---- stage K and Vt (16 x 1KB regions each), swizzled; 4 waves
#pragma unroll
        for (int j = 0; j < 4; ++j) {
            const int reg  = wave * 4 + j;
            const int rowK = reg * 4 + (lane >> 4);
            const int cK   = (lane & 15) ^ (rowK & 7);
            g2l16(Kg + (size_t)(bh * SEQ + k0 + rowK) * HD + cK * 8, Ks + reg * 512);
            const int rowV = reg * 8 + (lane >> 3);
            const int cV   = (lane & 7) ^ (rowV & 7);
            g2l16(Vt + (size_t)(bh * HD + rowV) * SEQ + k0 + cV * 8, Vs + reg * 512);
        }
        __syncthreads();

        if (k0 <= qrow0 + 31) {          // wave has work (strip1 at least)
            const bool act0 = (k0 <= qrow0 + 15);
            const int swz = l16 & 7;
            // ---- S^T = K Q^T for both strips; kf read once, used twice
            f32x4 s0[4], s1[4];
#pragma unroll
            for (int t = 0; t < 4; ++t) {
                f32x4 a0 = (f32x4){0.f, 0.f, 0.f, 0.f};
                f32x4 a1 = (f32x4){0.f, 0.f, 0.f, 0.f};
#pragma unroll
                for (int kc = 0; kc < 4; ++kc) {
                    bf16x8 kf = *(const bf16x8*)(Ks + (t * 16 + l16) * 128 +
                                                 (((kc * 4 + quad) ^ swz) * 8));
                    if (act0) a0 = MFMA16(kf, qf0[kc], a0);
                    a1 = MFMA16(kf, qf1[kc], a1);
                }
#pragma unroll
                for (int r = 0; r < 4; ++r) { s0[t][r] = a0[r] * sl2; s1[t][r] = a1[r] * sl2; }
            }
            // ---- causal mask per strip (diagonal-overlap tiles only)
            if (act0 && k0 + 63 > qrow0) {
                const int q = qrow0 + l16;
#pragma unroll
                for (int t = 0; t < 4; ++t)
#pragma unroll
                    for (int r = 0; r < 4; ++r)
                        if (k0 + t * 16 + quad * 4 + r > q) s0[t][r] = -INFINITY;
            }
            if (k0 + 63 > qrow0 + 16) {
                const int q = qrow0 + 16 + l16;
#pragma unroll
                for (int t = 0; t < 4; ++t)
#pragma unroll
                    for (int r = 0; r < 4; ++r)
                        if (k0 + t * 16 + quad * 4 + r > q) s1[t][r] = -INFINITY;
            }
            // ---- online softmax strip0
            if (act0) {
                float vm = s0[0][0];
#pragma unroll
                for (int t = 0; t < 4; ++t)
#pragma unroll
                    for (int r = 0; r < 4; ++r) vm = fmaxf(vm, s0[t][r]);
                vm = fmaxf(vm, __shfl_xor(vm, 16));
                vm = fmaxf(vm, __shfl_xor(vm, 32));
                const float mn = fmaxf(m0, vm);
                const float alpha = __builtin_amdgcn_exp2f(m0 - mn);
                m0 = mn;
                float ps = 0.f;
#pragma unroll
                for (int t = 0; t < 4; ++t)
#pragma unroll
                    for (int r = 0; r < 4; ++r) {
                        const float p = __builtin_amdgcn_exp2f(s0[t][r] - mn);
                        s0[t][r] = p;
                        ps += p;
                    }
                ps += __shfl_xor(ps, 16);
                ps += __shfl_xor(ps, 32);
                l0 = l0 * alpha + ps;
#pragma unroll
                for (int ot = 0; ot < 8; ++ot)
#pragma unroll
                    for (int r = 0; r < 4; ++r) o0[ot][r] *= alpha;
#pragma unroll
                for (int t = 0; t < 4; ++t) {
                    bf16x4 pk;
#pragma unroll
                    for (int r = 0; r < 4; ++r) pk[r] = (__bf16)s0[t][r];
                    *(bf16x4*)(Pw + l16 * 72 + t * 16 + quad * 4) = pk;
                }
            }
            // ---- online softmax strip1 (always active here)
            {
                float vm = s1[0][0];
#pragma unroll
                for (int t = 0; t < 4; ++t)
#pragma unroll
                    for (int r = 0; r < 4; ++r) vm = fmaxf(vm, s1[t][r]);
                vm = fmaxf(vm, __shfl_xor(vm, 16));
                vm = fmaxf(vm, __shfl_xor(vm, 32));
                const float mn = fmaxf(m1, vm);
                const float alpha = __builtin_amdgcn_exp2f(m1 - mn);
                m1 = mn;
                float ps = 0.f;
#pragma unroll
                for (int t = 0; t < 4; ++t)
#pragma unroll
                    for (int r = 0; r < 4; ++r) {
                        const float p = __builtin_amdgcn_exp2f(s1[t][r] - mn);
                        s1[t][r] = p;
                        ps += p;
                    }
                ps += __shfl_xor(ps, 16);
                ps += __shfl_xor(ps, 32);
                l1 = l1 * alpha + ps;
#pragma unroll
                for (int ot = 0; ot < 8; ++ot)
#pragma unroll
                    for (int r = 0; r < 4; ++r) o1[ot][r] *= alpha;
#pragma unroll
                for (int t = 0; t < 4; ++t) {
                    bf16x4 pk;
#pragma unroll
                    for (int r = 0; r < 4; ++r) pk[r] = (__bf16)s1[t][r];
                    *(bf16x4*)(Pw + (16 + l16) * 72 + t * 16 + quad * 4) = pk;
                }
            }
            // ---- O^T += V^T P^T ; vf read once, used for both strips
#pragma unroll
            for (int kk = 0; kk < 2; ++kk) {
                bf16x8 pf0, pf1;
                if (act0) pf0 = *(const bf16x8*)(Pw + l16 * 72 + kk * 32 + quad * 8);
                pf1 = *(const bf16x8*)(Pw + (16 + l16) * 72 + kk * 32 + quad * 8);
#pragma unroll
                for (int ot = 0; ot < 8; ++ot) {
                    bf16x8 vf = *(const bf16x8*)(Vs + (ot * 16 + l16) * 64 +
                                                 (((kk * 4 + quad) ^ swz) * 8));
                    if (act0) o0[ot] = MFMA16(vf, pf0, o0[ot]);
                    o1[ot] = MFMA16(vf, pf1, o1[ot]);
                }
            }
        }
    }

    // epilogue: O[b, s, h*128 + d], d = ot*16 + quad*4 + r (8B stores)
    const int b = bh >> 4, h = bh & (NH - 1);
    const float inv0 = 1.0f / l0, inv1 = 1.0f / l1;
    __bf16* or0 = O + ((size_t)(b * SEQ + qrow0 + l16)) * DM + h * HD;
    __bf16* or1 = or0 + (size_t)16 * DM;
#pragma unroll
    for (int ot = 0; ot < 8; ++ot) {
        bf16x4 ov0, ov1;
#pragma unroll
        for (int r = 0; r < 4; ++r) {
            ov0[r] = (__bf16)(o0[ot][r] * inv0);
            ov1[r] = (__bf16)(o1[ot][r] * inv1);
        }
        *(bf16x4*)(or0 + ot * 16 + quad * 4) = ov0;
        *(bf16x4*)(or1 + ot * 16 + quad * 4) = ov1;
    }
}

// ---------------------------------------------------------------------------
extern "C" void kernel_launch(void* const* d_in, const int* in_sizes, int n_in,
                              void* d_out, int out_size, void* d_ws, size_t ws_size,
                              hipStream_t stream) {
    (void)in_sizes; (void)n_in; (void)out_size; (void)ws_size;
    const float* x  = (const float*)d_in[0];
    const float* Wq = (const float*)d_in[1];
    const float* bq = (const float*)d_in[2];
    const float* Wk = (const float*)d_in[3];
    const float* bk = (const float*)d_in[4];
    const float* Wv = (const float*)d_in[5];
    const float* bv = (const float*)d_in[6];
    const float* Wo = (const float*)d_in[7];
    const float* bo = (const float*)d_in[8];

    char* ws = (char*)d_ws;
    const size_t WT = (size_t)DM * DM * 2;      // 8 MB per transposed bf16 weight
    const size_t XB = (size_t)MROWS * DM * 2;   // 33.5 MB per bf16 activation
    __bf16* WTs = (__bf16*)ws;                  // WqT;WkT;WvT;WoT contiguous
    __bf16* WoT = (__bf16*)(ws + 3 * WT);
    __bf16* xb  = (__bf16*)(ws + 4 * WT + 0 * XB);
    __bf16* Qb  = (__bf16*)(ws + 4 * WT + 1 * XB);  // Qb/Kb contiguous ([2][B,H,S,D])
    __bf16* Kb  = (__bf16*)(ws + 4 * WT + 2 * XB);
    __bf16* Vtb = (__bf16*)(ws + 4 * WT + 3 * XB);  // V written directly as [B,H,D,S]
    __bf16* Ob  = xb;   // x is dead after the QKV projection (fa writes Ob in epilogue only)

    const dim3 tb(32, 8);
    prep_fused<<<16384 + 8192, tb, 0, stream>>>(x, Wq, Wk, Wv, Wo, xb, WTs);

    // Fused QKV projection: [8192,2048] x [2048,6144]; V lands pre-transposed
    gemm_bt<0><<<dim3(64, 48), 256, 0, stream>>>(xb, WTs, bq, bk, bv, Qb, Vtb);

    fa_fwd<<<dim3(SEQ / 128, 4 * NH), 256, 0, stream>>>(Qb, Kb, Vtb, Ob);

    gemm_bt<1><<<dim3(64, 16), 256, 0, stream>>>(Ob, WoT, bo, nullptr, nullptr,
                                                 (float*)d_out, nullptr);
}

// Round 7
// 703.339 us; speedup vs baseline: 1.7361x; 1.7361x over previous
//
#include <hip/hip_runtime.h>
#include <hip/hip_bf16.h>
#include <math.h>

// Problem constants (CausalSelfAttention: B=4, S=2048, Dm=2048, H=16, Hd=128)
// Inputs/outputs are FP32 (per reference); compute in bf16 MFMA w/ fp32 accum.
#define SEQ   2048
#define DM    2048
#define NH    16
#define HD    128
#define MROWS 8192   // B*S

typedef __bf16 bf16x8 __attribute__((ext_vector_type(8)));
typedef __bf16 bf16x4 __attribute__((ext_vector_type(4)));
typedef float  f32x4  __attribute__((ext_vector_type(4)));

#define MFMA16(a, b, c) __builtin_amdgcn_mfma_f32_16x16x32_bf16((a), (b), (c), 0, 0, 0)

__device__ __forceinline__ void g2l16(const void* g, void* l) {
    __builtin_amdgcn_global_load_lds(
        (const __attribute__((address_space(1))) void*)g,
        (__attribute__((address_space(3))) void*)l, 16, 0, 0);
}

// ---------------------------------------------------------------------------
// Fused prep: blocks [0,16384): transpose+convert the 4 weights
//             blocks [16384, 24576): elementwise x fp32->bf16
// ---------------------------------------------------------------------------
__global__ void prep_fused(const float* __restrict__ x,
                           const float* __restrict__ s0,
                           const float* __restrict__ s1,
                           const float* __restrict__ s2,
                           const float* __restrict__ s3,
                           __bf16* __restrict__ xb,
                           __bf16* __restrict__ wdst) {
    const int bx = blockIdx.x;
    if (bx < 16384) {
        __shared__ float t[32][33];
        const int z = bx >> 12, rem = bx & 4095;
        const float* src = (z == 0) ? s0 : (z == 1) ? s1 : (z == 2) ? s2 : s3;
        __bf16* d = wdst + (size_t)z * DM * DM;
        const int c0 = (rem & 63) * 32, r0 = (rem >> 6) * 32;
        for (int i = threadIdx.y; i < 32; i += 8)
            t[i][threadIdx.x] = src[(size_t)(r0 + i) * DM + c0 + threadIdx.x];
        __syncthreads();
        for (int i = threadIdx.y; i < 32; i += 8)
            d[(size_t)(c0 + i) * DM + r0 + threadIdx.x] = (__bf16)t[threadIdx.x][i];
    } else {
        const int tid = threadIdx.y * 32 + threadIdx.x;
        const size_t i0 = (((size_t)(bx - 16384)) * 256 + tid) * 8;
        if (i0 + 8 <= (size_t)MROWS * DM) {
            f32x4 a = *(const f32x4*)(x + i0);
            f32x4 b = *(const f32x4*)(x + i0 + 4);
            bf16x8 o;
#pragma unroll
            for (int j = 0; j < 4; ++j) { o[j] = (__bf16)a[j]; o[4 + j] = (__bf16)b[j]; }
            *(bf16x8*)(xb + i0) = o;
        }
    }
}

// ---------------------------------------------------------------------------
// GEMM (m97 structure + XOR bank swizzle): C[M,N] = A[M,K]*Bt[N,K]^T + bias
// 128x128 tile, BK=32, 4 waves in 2x2, each wave 64x64 via 4x4 MFMA 16x16x32.
// MODE 0: fused QKV — Bt is [3*DM, DM] (WqT;WkT;WvT).
//         proj 0/1 (Q,K): bf16 to [2][B,H,S,D] via Cout_.
//         proj 2   (V)  : bf16 to Vt_[B,H,D,S] via per-wave LDS transpose.
// MODE 1: final proj — fp32 flat [M, DM] to Cout_.
// ---------------------------------------------------------------------------
template <int MODE>
__global__ __launch_bounds__(256) void gemm_bt(const __bf16* __restrict__ A,
                                               const __bf16* __restrict__ Bt,
                                               const float* __restrict__ b0,
                                               const float* __restrict__ b1,
                                               const float* __restrict__ b2,
                                               void* __restrict__ Cout_,
                                               __bf16* __restrict__ Vt_) {
    constexpr int K = DM;
    // 9216 elem = max(staging 8192, epilogue-transpose 4 waves x 32 x 72)
    __shared__ __bf16 smem[9216];
    __bf16* As = smem;
    __bf16* Bs = smem + 4096;
    const int tid  = threadIdx.x;
    const int wave = tid >> 6, lane = tid & 63;
    const int quad = lane >> 4, l16 = lane & 15;
    const int bm = blockIdx.x * 128, bn = blockIdx.y * 128;
    const int wm = (wave >> 1) * 64, wn = (wave & 1) * 64;

    const int proj = (MODE == 0) ? (bn >> 11) : 0;               // block-uniform
    const float* bias = (MODE == 0) ? (proj == 0 ? b0 : (proj == 1 ? b1 : b2)) : b0;

    f32x4 acc[4][4];
#pragma unroll
    for (int i = 0; i < 4; ++i)
#pragma unroll
        for (int j = 0; j < 4; ++j) acc[i][j] = (f32x4){0.f, 0.f, 0.f, 0.f};

    // staging source chunk swizzle: slot (lane&3) holds global chunk c
    const int srow = (lane >> 2);                  // row within 16-row region
    const int sc   = (lane & 3) ^ ((lane >> 3) & 3);
    // fragment read chunk swizzle
    const int rswz = (l16 >> 1) & 3;

    for (int k0 = 0; k0 < K; k0 += 32) {
        __syncthreads();
#pragma unroll
        for (int j = 0; j < 2; ++j) {
            const int region = wave + 4 * j;              // 0..7, 1KB regions
            const int row    = region * 16 + srow;        // 0..127
            g2l16(A  + (size_t)(bm + row) * K + k0 + sc * 8, As + region * 512);
            g2l16(Bt + (size_t)(bn + row) * K + k0 + sc * 8, Bs + region * 512);
        }
        __syncthreads();

        bf16x8 af[4], bf[4];
#pragma unroll
        for (int i = 0; i < 4; ++i)
            af[i] = *(const bf16x8*)(As + (wm + i * 16 + l16) * 32 + (quad ^ rswz) * 8);
#pragma unroll
        for (int j = 0; j < 4; ++j)
            bf[j] = *(const bf16x8*)(Bs + (wn + j * 16 + l16) * 32 + (quad ^ rswz) * 8);
#pragma unroll
        for (int i = 0; i < 4; ++i)
#pragma unroll
            for (int j = 0; j < 4; ++j) acc[i][j] = MFMA16(af[i], bf[j], acc[i][j]);
    }

    if (MODE == 0 && proj == 2) {
        // V epilogue: transpose 64x64 wave chunk through LDS, emit [B,H,D,S].
        __syncthreads();                       // all waves done reading As/Bs
        __bf16* wb = smem + wave * 2304;       // 32 x 72 per wave
        const int b = bm >> 11;
        const int rrow = lane >> 3, cch = lane & 7;
#pragma unroll
        for (int hp = 0; hp < 2; ++hp) {
            // write transposed [n][m] rows, b64-packed over r (consecutive m)
#pragma unroll
            for (int j2 = 0; j2 < 2; ++j2) {
                const int j = hp * 2 + j2;
                const int n = (bn + wn + j * 16 + l16) & (DM - 1);
                const float bia = bias[n];
#pragma unroll
                for (int i = 0; i < 4; ++i) {
                    bf16x4 pk;
#pragma unroll
                    for (int r = 0; r < 4; ++r) pk[r] = (__bf16)(acc[i][j][r] + bia);
                    *(bf16x4*)(wb + (j2 * 16 + l16) * 72 + i * 16 + quad * 4) = pk;
                }
            }
            // read rows along m, store 16B-coalesced along s
#pragma unroll
            for (int p = 0; p < 4; ++p) {
                const int nrel  = p * 8 + rrow;            // 0..31
                const int d_loc = hp * 32 + nrel;          // 0..63
                const int n = (bn + wn + d_loc) & (DM - 1);
                const int h = n >> 7, d = n & (HD - 1);
                bf16x8 v = *(const bf16x8*)(wb + nrel * 72 + cch * 8);
                const int s = (bm & (SEQ - 1)) + wm + cch * 8;
                *(bf16x8*)(Vt_ + ((size_t)((b * NH + h) * HD + d)) * SEQ + s) = v;
            }
        }
        return;
    }

#pragma unroll
    for (int i = 0; i < 4; ++i)
#pragma unroll
        for (int j = 0; j < 4; ++j)
#pragma unroll
            for (int r = 0; r < 4; ++r) {
                const int m  = bm + wm + i * 16 + quad * 4 + r;
                const int n3 = bn + wn + j * 16 + l16;
                const int n  = (MODE == 0) ? (n3 & (DM - 1)) : n3;
                const float v = acc[i][j][r] + bias[n];
                if (MODE == 0) {
                    const int b = m >> 11, s = m & (SEQ - 1);
                    const int h = n >> 7, d = n & (HD - 1);
                    ((__bf16*)Cout_)[(size_t)proj * MROWS * DM +
                                     ((size_t)((b * NH + h) * SEQ + s)) * HD + d] = (__bf16)v;
                } else {
                    ((float*)Cout_)[(size_t)m * DM + n] = v;
                }
            }
}

// ---------------------------------------------------------------------------
// Flash attention fwd, causal — TRANSPOSED-S formulation (Round-5 config:
// 512 threads = 8 waves x 16 q-rows = 128 q; the 2-strip variant of R6
// blew VGPR to 216 -> 6% occupancy -> 4x slower. Keep single strip.)
// S^T = K·Q^T: lane=query, regs=keys; softmax = in-reg ops + 2 shuffles;
// P^T packs as ds_write_b64, reads back b128; PV computes O^T = V^T·P^T.
// Ks/Vs XOR-swizzled (chunk c -> slot c^(row&7)); P^T stride 72.
// blockIdx.x REVERSED so heavy (many-k-tile) blocks dispatch first.
// ---------------------------------------------------------------------------
__global__ __launch_bounds__(512) void fa_fwd(const __bf16* __restrict__ Q,
                                              const __bf16* __restrict__ Kg,
                                              const __bf16* __restrict__ Vt,
                                              __bf16* __restrict__ O) {
    __shared__ __bf16 Ks[64 * 128];     // [key][d] swizzled       16KB
    __shared__ __bf16 Vs[128 * 64];     // [d][key] swizzled       16KB
    __shared__ __bf16 Pt[8][16 * 72];   // per-wave P^T as [q][key] 18KB
    const int tid  = threadIdx.x;
    const int wave = tid >> 6, lane = tid & 63;
    const int quad = lane >> 4, l16 = lane & 15;
    const int bh = blockIdx.y;          // b*NH + h
    const int bx = gridDim.x - 1 - blockIdx.x;
    const int q0 = bx * 128;
    const int qrow0 = q0 + wave * 16;   // this wave's 16 query rows
    __bf16* Pw = &Pt[wave][0];

    // Q B-fragments: lane holds Q[qrow0+l16][kc*32+quad*8..+7]
    bf16x8 qf[4];
    const __bf16* qrow = Q + (size_t)(bh * SEQ + qrow0 + l16) * HD;
#pragma unroll
    for (int kc = 0; kc < 4; ++kc) qf[kc] = *(const bf16x8*)(qrow + kc * 32 + quad * 8);

    float m_q = -INFINITY, l_q = 0.f;   // per-lane: query q = qrow0 + l16
    f32x4 oacc[8];                      // O^T: d = ot*16 + quad*4 + r, q = l16
#pragma unroll
    for (int ot = 0; ot < 8; ++ot) oacc[ot] = (f32x4){0.f, 0.f, 0.f, 0.f};

    const float sl2 = 0.08838834764831845f * 1.4426950408889634f;  // scale*log2(e)

    const int ntiles = bx * 2 + 2;      // keys up to q0+127
    for (int kt = 0; kt < ntiles; ++kt) {
        const int k0 = kt * 64;
        __syncthreads();  // protect Ks/Vs from overwrite while prev iter reads
        // ---- stage K and Vt (16 x 1KB regions each), swizzled
#pragma unroll
        for (int j = 0; j < 2; ++j) {
            const int reg  = wave * 2 + j;
            const int rowK = reg * 4 + (lane >> 4);           // 0..63
            const int cK   = (lane & 15) ^ (rowK & 7);        // 16B chunk 0..15
            g2l16(Kg + (size_t)(bh * SEQ + k0 + rowK) * HD + cK * 8, Ks + reg * 512);
            const int rowV = reg * 8 + (lane >> 3);           // 0..127
            const int cV   = (lane & 7) ^ (rowV & 7);         // 16B chunk 0..7
            g2l16(Vt + (size_t)(bh * HD + rowV) * SEQ + k0 + cV * 8, Vs + reg * 512);
        }
        __syncthreads();

        if (k0 <= qrow0 + 15) {         // wave has unmasked work in this tile
            const int swz = l16 & 7;
            // ---- S^T = K Q^T (scaled): tile t rows = keys t*16+quad*4+r, col q=l16
            f32x4 st[4];
#pragma unroll
            for (int t = 0; t < 4; ++t) {
                f32x4 a = (f32x4){0.f, 0.f, 0.f, 0.f};
#pragma unroll
                for (int kc = 0; kc < 4; ++kc) {
                    bf16x8 kf = *(const bf16x8*)(Ks + (t * 16 + l16) * 128 +
                                                 (((kc * 4 + quad) ^ swz) * 8));
                    a = MFMA16(kf, qf[kc], a);        // A = K, B = Q
                }
#pragma unroll
                for (int r = 0; r < 4; ++r) st[t][r] = a[r] * sl2;
            }
            // ---- causal mask (diagonal only lives in the last two tiles)
            if (kt >= ntiles - 2) {
                const int q = qrow0 + l16;
#pragma unroll
                for (int t = 0; t < 4; ++t)
#pragma unroll
                    for (int r = 0; r < 4; ++r) {
                        const int key = k0 + t * 16 + quad * 4 + r;
                        if (key > q) st[t][r] = -INFINITY;
                    }
            }
            // ---- online softmax over keys (regs + quads)
            float vm = st[0][0];
#pragma unroll
            for (int t = 0; t < 4; ++t)
#pragma unroll
                for (int r = 0; r < 4; ++r) vm = fmaxf(vm, st[t][r]);
            vm = fmaxf(vm, __shfl_xor(vm, 16));
            vm = fmaxf(vm, __shfl_xor(vm, 32));
            const float mn = fmaxf(m_q, vm);
            const float alpha = __builtin_amdgcn_exp2f(m_q - mn);
            m_q = mn;
            float ps = 0.f;
#pragma unroll
            for (int t = 0; t < 4; ++t)
#pragma unroll
                for (int r = 0; r < 4; ++r) {
                    const float p = __builtin_amdgcn_exp2f(st[t][r] - mn);
                    st[t][r] = p;
                    ps += p;
                }
            ps += __shfl_xor(ps, 16);
            ps += __shfl_xor(ps, 32);
            l_q = l_q * alpha + ps;
#pragma unroll
            for (int ot = 0; ot < 8; ++ot)
#pragma unroll
                for (int r = 0; r < 4; ++r) oacc[ot][r] *= alpha;

            // ---- P^T rows: lane writes 4 consecutive keys at row q=l16 (b64)
#pragma unroll
            for (int t = 0; t < 4; ++t) {
                bf16x4 pk;
#pragma unroll
                for (int r = 0; r < 4; ++r) pk[r] = (__bf16)st[t][r];
                *(bf16x4*)(Pw + l16 * 72 + t * 16 + quad * 4) = pk;
            }
            // (Pw wave-private; compiler inserts lgkmcnt before dependent reads)

            // ---- O^T += V^T P^T
#pragma unroll
            for (int kk = 0; kk < 2; ++kk) {
                bf16x8 pf = *(const bf16x8*)(Pw + l16 * 72 + kk * 32 + quad * 8);
#pragma unroll
                for (int ot = 0; ot < 8; ++ot) {
                    bf16x8 vf = *(const bf16x8*)(Vs + (ot * 16 + l16) * 64 +
                                                 (((kk * 4 + quad) ^ swz) * 8));
                    oacc[ot] = MFMA16(vf, pf, oacc[ot]);   // A = V^T, B = P^T
                }
            }
        }
    }

    // epilogue: O[b, s=qrow0+l16, h*128 + d], d = ot*16 + quad*4 + r (8B stores)
    const int b = bh >> 4, h = bh & (NH - 1);
    const float inv = 1.0f / l_q;
    __bf16* orow = O + ((size_t)(b * SEQ + qrow0 + l16)) * DM + h * HD;
#pragma unroll
    for (int ot = 0; ot < 8; ++ot) {
        bf16x4 ov;
#pragma unroll
        for (int r = 0; r < 4; ++r) ov[r] = (__bf16)(oacc[ot][r] * inv);
        *(bf16x4*)(orow + ot * 16 + quad * 4) = ov;
    }
}

// ---------------------------------------------------------------------------
extern "C" void kernel_launch(void* const* d_in, const int* in_sizes, int n_in,
                              void* d_out, int out_size, void* d_ws, size_t ws_size,
                              hipStream_t stream) {
    (void)in_sizes; (void)n_in; (void)out_size; (void)ws_size;
    const float* x  = (const float*)d_in[0];
    const float* Wq = (const float*)d_in[1];
    const float* bq = (const float*)d_in[2];
    const float* Wk = (const float*)d_in[3];
    const float* bk = (const float*)d_in[4];
    const float* Wv = (const float*)d_in[5];
    const float* bv = (const float*)d_in[6];
    const float* Wo = (const float*)d_in[7];
    const float* bo = (const float*)d_in[8];

    char* ws = (char*)d_ws;
    const size_t WT = (size_t)DM * DM * 2;      // 8 MB per transposed bf16 weight
    const size_t XB = (size_t)MROWS * DM * 2;   // 33.5 MB per bf16 activation
    __bf16* WTs = (__bf16*)ws;                  // WqT;WkT;WvT;WoT contiguous
    __bf16* WoT = (__bf16*)(ws + 3 * WT);
    __bf16* xb  = (__bf16*)(ws + 4 * WT + 0 * XB);
    __bf16* Qb  = (__bf16*)(ws + 4 * WT + 1 * XB);  // Qb/Kb contiguous
    __bf16* Kb  = (__bf16*)(ws + 4 * WT + 2 * XB);
    __bf16* Vtb = (__bf16*)(ws + 4 * WT + 3 * XB);  // V written directly as [B,H,D,S]
    __bf16* Ob  = xb;   // x is dead after the QKV projection

    const dim3 tb(32, 8);
    prep_fused<<<16384 + 8192, tb, 0, stream>>>(x, Wq, Wk, Wv, Wo, xb, WTs);

    // Fused QKV projection: [8192,2048] x [2048,6144]; V lands pre-transposed
    gemm_bt<0><<<dim3(64, 48), 256, 0, stream>>>(xb, WTs, bq, bk, bv, Qb, Vtb);

    fa_fwd<<<dim3(SEQ / 128, 4 * NH), 512, 0, stream>>>(Qb, Kb, Vtb, Ob);

    gemm_bt<1><<<dim3(64, 16), 256, 0, stream>>>(Ob, WoT, bo, nullptr, nullptr,
                                                 (float*)d_out, nullptr);
}